// Round 17
// baseline (386.243 us; speedup 1.0000x reference)
//
#include <hip/hip_runtime.h>
#include <hip/hip_bf16.h>

// ---------------------------------------------------------------------------
// multihead_attentive_layer: bf16 MFMA pipeline  (round-17 = round-16 +
// grid-stride LN (2048 blocks x 8 rows; 16384 one-row blocks were
// dispatch-rate-limited at ~2000 blk/us -- r12/r13 calibration)).
//   prep: cast q,v -> bf16 ; transpose weights -> bf16 [N][K]
//   QKV:  Qh = q@W1' (pre-scaled), Kh = v@W2', Vt = W3'' @ v^T
//   FA:   flash attention (8w x 32q, KVBLK=64, 4-deep bufs, raw-barrier +
//         interleaved staging + vmcnt(2); swapped-operand, softmax-free)
//   G4:   proj = cat @ Wp + bp + qbf(bf16 residual)  -> bf16
//   LN1 -> pln bf16 ; G5: t = relu(pln @ Wt + bt) + pln -> bf16 ; LN2 -> f32
// GEMMs: 256x256 tile, BK=64, interleaved staging + vmcnt(2), granule-XOR
// LDS swizzle, setprio (GEMM only; r11: FA setprio perturbs regalloc),
// XCD swizzle. 7 launches.
// ---------------------------------------------------------------------------

typedef __bf16 bf16x8 __attribute__((ext_vector_type(8)));
typedef float  f32x4  __attribute__((ext_vector_type(4)));
typedef float  f32x16 __attribute__((ext_vector_type(16)));
typedef unsigned u32x4 __attribute__((ext_vector_type(4)));

#define GLDS16(g, l)                                                         \
  __builtin_amdgcn_global_load_lds(                                          \
      (__attribute__((address_space(1))) void*)(g),                          \
      (__attribute__((address_space(3))) void*)(l), 16, 0, 0)

__device__ __forceinline__ unsigned short f2bfu(float f) {
  unsigned int u = __builtin_bit_cast(unsigned int, f);
  u += 0x7fffu + ((u >> 16) & 1u);   // RNE (finite values only)
  return (unsigned short)(u >> 16);
}
__device__ __forceinline__ float bfu2f(unsigned short u) {
  return __builtin_bit_cast(float, (unsigned int)u << 16);
}

// ---------------- prep: casts + weight transposes, one launch --------------
__device__ __forceinline__ void tc_body(const float* in, unsigned short* out,
                                        int R, int C, int c0, int r0,
                                        int tx, int ty) {
  __shared__ float tile[32][33];
#pragma unroll
  for (int j = 0; j < 4; j++)
    tile[ty + j * 8][tx] = in[(size_t)(r0 + ty + j * 8) * C + c0 + tx];
  __syncthreads();
#pragma unroll
  for (int j = 0; j < 4; j++)
    out[(size_t)(c0 + ty + j * 8) * R + r0 + tx] = f2bfu(tile[tx][ty + j * 8]);
}

// 1-D grid, 9216 blocks, zero waste (branch is blockIdx-uniform):
//   idx < 4096           : cast query (idx<2048) / value, grid-stride x8
//   idx in [4096, 7168)  : {W1,W2,W3} x 8 head-slices (1024x128)
//   idx in [7168, 9216)  : Wp (first 1024) / Wt, 1024x1024
__global__ __launch_bounds__(256) void prep_fused(
    const float* __restrict__ query, const float* __restrict__ value,
    unsigned short* __restrict__ qbf, unsigned short* __restrict__ vbf,
    const float* __restrict__ W1, const float* __restrict__ W2,
    const float* __restrict__ W3, const float* __restrict__ Wp,
    const float* __restrict__ Wt, unsigned short* __restrict__ O1,
    unsigned short* __restrict__ O2, unsigned short* __restrict__ O3,
    unsigned short* __restrict__ Op, unsigned short* __restrict__ Ot) {
  int idx = blockIdx.x;
  if (idx < 4096) {
    const float* in = (idx < 2048) ? query : value;
    unsigned short* out = (idx < 2048) ? qbf : vbf;
    int blk = idx & 2047;
    int i = (blk * 256 + threadIdx.x) * 4;
    const int stride = 2048 * 256 * 4;
    for (; i < 16777216; i += stride) {
      float4 v = *(const float4*)(in + i);
      ushort4 o;
      o.x = f2bfu(v.x); o.y = f2bfu(v.y); o.z = f2bfu(v.z); o.w = f2bfu(v.w);
      *(ushort4*)(out + i) = o;
    }
    return;
  }
  int t2 = idx - 4096;
  int tx = threadIdx.x & 31, ty = threadIdx.x >> 5;
  if (t2 < 3072) {
    int slice = t2 >> 7, blk = t2 & 127;
    int t = slice >> 3, s = slice & 7;
    const float* in = (t == 0 ? W1 : t == 1 ? W2 : W3) + (size_t)s * 1024 * 128;
    unsigned short* out = (t == 0 ? O1 : t == 1 ? O2 : O3) + (size_t)s * 1024 * 128;
    tc_body(in, out, 1024, 128, (blk & 3) * 32, (blk >> 2) * 32, tx, ty);
  } else {
    int idx2 = t2 - 3072;
    int zz = idx2 >> 10, blk = idx2 & 1023;
    tc_body(zz ? Wt : Wp, zz ? Ot : Op, 1024, 1024,
            (blk & 31) * 32, (blk >> 5) * 32, tx, ty);
  }
}

// --------------- GEMM 256x256 core, BK=64, interleaved staging -------------
// 512 thr = 8 waves (2M x 4N), each wave owns 128x64. LDS 128KB double buf,
// granule-XOR swizzle slot(r,g8)=g8^(r&7). Per K-tile:
//   barrier(a) [buf free] -> STAGE part0 (2 loads) -> vmcnt(2) [prev tile's
//   8 loads landed: FIFO] -> barrier(b) -> 4x {16-MFMA w/ setprio; issue
//   next stage part}.
__device__ __forceinline__ void gemm256_core(
    const char* gA, const char* gB, char* lds, f32x4 (&acc)[8][4], int tid) {
  int wid = tid >> 6, lane = tid & 63;
  int l15 = lane & 15, l4 = lane >> 4;
  int wm = (wid >> 2) * 128, wn = (wid & 3) * 64;

  // one part = 1 A-load + 1 B-load per thread (64 rows each of A and B)
  auto STAGE_PART = [&](int buf, int t, int part) {
    char* ab = lds + buf * 65536;
    char* bb = ab + 32768;
    int s = part * 512 + tid;
    int row = s >> 3;
    int g = (s & 7) ^ (row & 7);
    unsigned dst = (unsigned)((part * 512 + (tid & ~63)) * 16);
    GLDS16(gA + (size_t)row * 2048 + t * 128 + g * 16, ab + dst);
    GLDS16(gB + (size_t)row * 2048 + t * 128 + g * 16, bb + dst);
  };

#pragma unroll
  for (int p = 0; p < 4; p++) STAGE_PART(0, 0, p);

  for (int t = 0; t < 16; t++) {
    __builtin_amdgcn_sched_barrier(0);
    __builtin_amdgcn_s_barrier();            // (a) buf[(t+1)&1] free to overwrite
    if (t < 15) {
      STAGE_PART((t + 1) & 1, t + 1, 0);     // 2 loads now; parts 1-3 mid-compute
      asm volatile("s_waitcnt vmcnt(2)" ::: "memory");   // tile t fully landed
    } else {
      asm volatile("s_waitcnt vmcnt(0)" ::: "memory");
    }
    __builtin_amdgcn_s_barrier();            // (b) tile t visible to all waves
    __builtin_amdgcn_sched_barrier(0);

    const char* ab = lds + (t & 1) * 65536;
    const char* bb = ab + 32768;
#pragma unroll
    for (int kk = 0; kk < 2; kk++) {
      bf16x8 bfr[4];
#pragma unroll
      for (int nf = 0; nf < 4; nf++) {
        int r = wn + nf * 16 + l15;
        bfr[nf] = *(const bf16x8*)(bb + r * 128 + (((kk * 4 + l4) ^ (r & 7)) << 4));
      }
#pragma unroll
      for (int mh = 0; mh < 2; mh++) {
        bf16x8 af[4];
#pragma unroll
        for (int mf = 0; mf < 4; mf++) {
          int r = wm + mh * 64 + mf * 16 + l15;
          af[mf] = *(const bf16x8*)(ab + r * 128 + (((kk * 4 + l4) ^ (r & 7)) << 4));
        }
        __builtin_amdgcn_s_setprio(1);
#pragma unroll
        for (int mf = 0; mf < 4; mf++)
#pragma unroll
          for (int nf = 0; nf < 4; nf++)
            acc[mh * 4 + mf][nf] = __builtin_amdgcn_mfma_f32_16x16x32_bf16(
                af[mf], bfr[nf], acc[mh * 4 + mf][nf], 0, 0, 0);
        __builtin_amdgcn_s_setprio(0);
        int grp = kk * 2 + mh;               // 0..3
        if (t < 15 && grp < 3) STAGE_PART((t + 1) & 1, t + 1, grp + 1);
      }
    }
  }
}

// ---------------- fused QKV projections (one launch, 768 blocks) -----------
// idx < 256 : Q tile of [16384,1024] = qbf @ Wq_t^T -> Qh scatter (scaled)
// idx < 512 : K tile, vbf @ Wk_t^T -> Kh scatter
// idx >= 512: V batched [1024,2048] = Wv_t @ vbf_b^T -> Vt (ld 2048)
__global__ __launch_bounds__(512, 2) void gemm_qkv(
    const unsigned short* __restrict__ qbf, const unsigned short* __restrict__ vbf,
    const unsigned short* __restrict__ Wq_t, const unsigned short* __restrict__ Wk_t,
    const unsigned short* __restrict__ Wv_t, unsigned short* __restrict__ Qh,
    unsigned short* __restrict__ Kh, unsigned short* __restrict__ Vt,
    float qscale) {
  int nb = gridDim.x;                  // 768 (mult of 8)
  int qq = nb >> 3;
  int lin = blockIdx.x;
  int idx = (lin & 7) * qq + (lin >> 3);       // XCD-contiguous (bijective)

  const unsigned short *A, *Bt;
  unsigned short* outp;
  int m0, n0, mode;
  float sc = 1.0f;
  if (idx < 512) {
    int seg = idx >> 8;                        // 0=Q, 1=K
    int t = idx & 255;                         // 64 m-tiles x 4 n-tiles
    m0 = (t >> 2) * 256; n0 = (t & 3) * 256;
    A = seg ? vbf : qbf;
    Bt = seg ? Wk_t : Wq_t;
    outp = seg ? Kh : Qh;
    if (!seg) sc = qscale;
    mode = 0;
  } else {
    int v = idx - 512;
    int bz = v >> 5, t = v & 31;               // 4 m-tiles x 8 n-tiles
    m0 = (t >> 3) * 256; n0 = (t & 7) * 256;
    A = Wv_t;
    Bt = vbf + (size_t)bz * 2048 * 1024;
    outp = Vt + (size_t)bz * 1024 * 2048;
    mode = 1;
  }

  __shared__ alignas(16) char lds[131072];
  f32x4 acc[8][4];
#pragma unroll
  for (int i = 0; i < 8; i++)
#pragma unroll
    for (int j = 0; j < 4; j++) acc[i][j] = (f32x4){0.f, 0.f, 0.f, 0.f};

  gemm256_core((const char*)A + (size_t)m0 * 2048,
               (const char*)Bt + (size_t)n0 * 2048, lds, acc, threadIdx.x);

  int tid = threadIdx.x, wid = tid >> 6, lane = tid & 63;
  int l15 = lane & 15, l4 = lane >> 4;
  int wm = (wid >> 2) * 128, wn = (wid & 3) * 64;
#pragma unroll
  for (int mi = 0; mi < 8; mi++)
#pragma unroll
    for (int nf = 0; nf < 4; nf++)
#pragma unroll
      for (int r = 0; r < 4; r++) {
        int gm = m0 + wm + mi * 16 + l4 * 4 + r;
        int gn = n0 + wn + nf * 16 + l15;
        float v = acc[mi][nf][r];
        if (mode == 0) {
          int b = gm >> 11, s = gm & 2047, h = gn >> 7, e = gn & 127;
          outp[((((size_t)b * 8 + h) * 2048 + s) << 7) + e] = f2bfu(v * sc);
        } else {
          outp[(size_t)gm * 2048 + gn] = f2bfu(v);
        }
      }
}

// ---------------- epilogue GEMMs (G4/G5), 256 blocks -----------------------
// MODE 2: out bf16 = acc + bias[n] + bf16 extra[m,n]   (proj pre-LN)
// MODE 3: out bf16 = relu(acc+bias) + bf16 extra[m,n]  (transform pre-LN)
template <int MODE>
__global__ __launch_bounds__(512, 2) void gemm256_ep(
    const unsigned short* __restrict__ A, const unsigned short* __restrict__ Bt,
    unsigned short* __restrict__ out, const float* __restrict__ bias,
    const unsigned short* __restrict__ extra) {
  int nb = gridDim.x;                  // 256
  int qq = nb >> 3;
  int lin = blockIdx.x;
  int idx = (lin & 7) * qq + (lin >> 3);
  int m0 = (idx >> 2) * 256, n0 = (idx & 3) * 256;

  __shared__ alignas(16) char lds[131072];
  f32x4 acc[8][4];
#pragma unroll
  for (int i = 0; i < 8; i++)
#pragma unroll
    for (int j = 0; j < 4; j++) acc[i][j] = (f32x4){0.f, 0.f, 0.f, 0.f};

  gemm256_core((const char*)A + (size_t)m0 * 2048,
               (const char*)Bt + (size_t)n0 * 2048, lds, acc, threadIdx.x);

  int tid = threadIdx.x, wid = tid >> 6, lane = tid & 63;
  int l15 = lane & 15, l4 = lane >> 4;
  int wm = (wid >> 2) * 128, wn = (wid & 3) * 64;
#pragma unroll
  for (int mi = 0; mi < 8; mi++)
#pragma unroll
    for (int nf = 0; nf < 4; nf++)
#pragma unroll
      for (int r = 0; r < 4; r++) {
        int gm = m0 + wm + mi * 16 + l4 * 4 + r;
        int gn = n0 + wn + nf * 16 + l15;
        float v = acc[mi][nf][r];
        float pl = bfu2f(extra[(size_t)gm * 1024 + gn]);
        if constexpr (MODE == 2)
          out[(size_t)gm * 1024 + gn] = f2bfu(v + bias[gn] + pl);
        else
          out[(size_t)gm * 1024 + gn] = f2bfu(fmaxf(v + bias[gn], 0.0f) + pl);
      }
}

// ------------------------------- flash attention ---------------------------
// grid (H, SQ/256, B), 512 thr (8 waves x 32 q-rows). KV tiles of 64, 4-deep
// buffered (128 KiB LDS). blockIdx.x = h -> (b,h) locality per XCD (T1).
// Swapped QK^T (S^T = mfma(K,Q): q lane-local) + softmax-free exp2 (scores
// bounded ~16 in log2 units; exp2(16)=65536 safe in f32) + swapped PV with
// in-register P^T pack (cvt_pk + permlane32_swap). l summed in epilogue.
// Sync per 2-kt window (interleaved staging): lgkm drain -> sbar(a) ->
// STAGE_K(kt+2) [2 loads] -> vmcnt(2) [prev window's 8 loads landed: FIFO]
// -> sbar(b) -> QK(kt); V(kt+2); QK(kt+1); K(kt+3); PV(kt); V(kt+3); PV(kt+1)
// NO setprio here (r11 A/B: it perturbs regalloc, -8%).
// 16-granule XOR swizzle on K and V (row&15), pre-swizzled global source.
__global__ __launch_bounds__(512) void fa_kernel(
    const unsigned short* __restrict__ Qh,   // [B][H][2048][128]
    const unsigned short* __restrict__ Kh,   // [B][H][2048][128]
    const unsigned short* __restrict__ Vt,   // [B][1024][2048]
    unsigned short* __restrict__ catO) {     // [B*2048][1024]
  int h = blockIdx.x, qt = blockIdx.y, b = blockIdx.z;
  int tid = threadIdx.x, wid = tid >> 6, lane = tid & 63;
  int q31 = lane & 31, hi = lane >> 5;

  __shared__ alignas(16) char lds[131072];
  // K buf (kt&3): lds + (kt&3)*16384      (64 rows x 256B)
  // V buf (kt&3): lds + 65536 + (kt&3)*16384 (64 rows x 256B; row r halves:
  //   V^T[e=r] / V^T[e=r+64]); both XOR-swizzled granule g -> g ^ (row&15).

  const char* gK = (const char*)(Kh + (((size_t)b * 8 + h) * 2048) * 128);
  const char* gV = (const char*)(Vt + ((size_t)b * 1024 + h * 128) * 2048);

  bf16x8 qf[8];
  {
    const char* gQ = (const char*)(Qh + (((size_t)b * 8 + h) * 2048
                        + (size_t)qt * 256 + wid * 32 + q31) * 128);
#pragma unroll
    for (int ks = 0; ks < 8; ks++)
      qf[ks] = *(const bf16x8*)(gQ + ks * 32 + hi * 16);
  }

  f32x16 o[4];
#pragma unroll
  for (int et = 0; et < 4; et++)
#pragma unroll
    for (int r = 0; r < 16; r++) o[et][r] = 0.f;
  float lacc0 = 0.f, lacc1 = 0.f;

  auto STAGE_K = [&](int kt) {
    char* kb = lds + (kt & 3) * 16384;
#pragma unroll
    for (int pass = 0; pass < 2; pass++) {
      int c = pass * 512 + tid;
      int row = c >> 4, ch = c & 15;
      int g = ch ^ (row & 15);
      GLDS16(gK + (size_t)(kt * 64 + row) * 256 + g * 16,
             kb + (pass * 512 + (tid & ~63)) * 16);
    }
  };
  auto STAGE_V = [&](int kt) {
    char* vb = lds + 65536 + (kt & 3) * 16384;
#pragma unroll
    for (int pass = 0; pass < 2; pass++) {
      int c = pass * 512 + tid;
      int row = c >> 4, g = c & 15;
      int gp = g ^ (row & 15);
      int e = ((gp >> 3) << 6) + row;
      GLDS16(gV + (size_t)e * 4096 + kt * 128 + (gp & 7) * 16,
             vb + (pass * 512 + (tid & ~63)) * 16);
    }
  };
  auto QK = [&](int kt, f32x16& r0, f32x16& r1) {
    const char* kb = lds + (kt & 3) * 16384;
#pragma unroll
    for (int r = 0; r < 16; r++) { r0[r] = 0.f; r1[r] = 0.f; }
#pragma unroll
    for (int ks = 0; ks < 8; ks++) {
      int g = ((2 * ks + hi) ^ (q31 & 15)) << 4;
      bf16x8 k0 = *(const bf16x8*)(kb + q31 * 256 + g);
      bf16x8 k1 = *(const bf16x8*)(kb + (q31 + 32) * 256 + g);
      r0 = __builtin_amdgcn_mfma_f32_32x32x16_bf16(k0, qf[ks], r0, 0, 0, 0);
      r1 = __builtin_amdgcn_mfma_f32_32x32x16_bf16(k1, qf[ks], r1, 0, 0, 0);
    }
  };
  auto SOFT_PV = [&](int kt, f32x16& s0, f32x16& s1) {
    float p[32];
#pragma unroll
    for (int r = 0; r < 16; r++) p[r] = __builtin_amdgcn_exp2f(s0[r]);
#pragma unroll
    for (int r = 0; r < 16; r++) p[16 + r] = __builtin_amdgcn_exp2f(s1[r]);
#pragma unroll
    for (int r = 0; r < 16; r++) { lacc0 += p[r]; lacc1 += p[16 + r]; }
    bf16x8 pa[4];
#pragma unroll
    for (int g = 0; g < 4; g++) {
      unsigned a0, a1, b0, b1;
      float p0 = p[g * 8 + 0], p1 = p[g * 8 + 1], p2 = p[g * 8 + 2], p3 = p[g * 8 + 3];
      float p4 = p[g * 8 + 4], p5 = p[g * 8 + 5], p6 = p[g * 8 + 6], p7 = p[g * 8 + 7];
      asm("v_cvt_pk_bf16_f32 %0, %1, %2" : "=v"(a0) : "v"(p0), "v"(p1));
      asm("v_cvt_pk_bf16_f32 %0, %1, %2" : "=v"(b0) : "v"(p4), "v"(p5));
      asm("v_cvt_pk_bf16_f32 %0, %1, %2" : "=v"(a1) : "v"(p2), "v"(p3));
      asm("v_cvt_pk_bf16_f32 %0, %1, %2" : "=v"(b1) : "v"(p6), "v"(p7));
      asm volatile("v_permlane32_swap_b32 %0, %1" : "+v"(a0), "+v"(b0));
      asm volatile("v_permlane32_swap_b32 %0, %1" : "+v"(a1), "+v"(b1));
      u32x4 w; w[0] = a0; w[1] = a1; w[2] = b0; w[3] = b1;
      pa[g] = __builtin_bit_cast(bf16x8, w);
    }
    const char* vb = lds + 65536 + (kt & 3) * 16384;
#pragma unroll
    for (int et = 0; et < 4; et++) {
      int row = (et & 1) * 32 + q31;
      int gb = (et >> 1) * 8;
#pragma unroll
      for (int ks = 0; ks < 4; ks++) {
        bf16x8 vf = *(const bf16x8*)(vb + row * 256 +
                        (((gb + 2 * ks + hi) ^ (row & 15)) << 4));
        o[et] = __builtin_amdgcn_mfma_f32_32x32x16_bf16(vf, pa[ks], o[et], 0, 0, 0);
      }
    }
  };

  // prologue: K/V for kt 0,1 in flight (8 gloads/thread)
  STAGE_K(0); STAGE_V(0); STAGE_K(1); STAGE_V(1);

  for (int w = 0; w < 16; w++) {
    int kt = 2 * w;
    asm volatile("s_waitcnt lgkmcnt(0)" ::: "memory");
    __builtin_amdgcn_sched_barrier(0);
    __builtin_amdgcn_s_barrier();          // (a) reads of overwrite targets done
    if (w < 15) {
      STAGE_K(kt + 2);                     // 2 loads now; rest mid-compute
      asm volatile("s_waitcnt vmcnt(2)" ::: "memory");  // prev window landed
    } else {
      asm volatile("s_waitcnt vmcnt(0)" ::: "memory");
    }
    __builtin_amdgcn_s_barrier();          // (b) bufs kt,kt+1 visible
    __builtin_amdgcn_sched_barrier(0);
    f32x16 sA0, sA1, sB0, sB1;
    QK(kt, sA0, sA1);
    if (w < 15) STAGE_V(kt + 2);
    QK(kt + 1, sB0, sB1);
    if (w < 15) STAGE_K(kt + 3);
    SOFT_PV(kt, sA0, sA1);
    if (w < 15) STAGE_V(kt + 3);
    SOFT_PV(kt + 1, sB0, sB1);
  }

  // --- epilogue: normalize, transpose via wave-private LDS, store ---
  float lacc = lacc0 + lacc1;
  lacc += __shfl_xor(lacc, 32);
  float linv = 1.0f / lacc;
  __syncthreads();                          // all waves done with K/V buffers
  char* reg = lds + wid * 8192;             // [32 q][256B e-row], swizzled &7
  int swz = (lane & 7) << 4;
#pragma unroll
  for (int et = 0; et < 4; et++)
#pragma unroll
    for (int pr = 0; pr < 8; pr++) {
      float lo = o[et][2 * pr] * linv, hf = o[et][2 * pr + 1] * linv;
      unsigned w;
      asm("v_cvt_pk_bf16_f32 %0, %1, %2" : "=v"(w) : "v"(lo), "v"(hf));
      int e = et * 32 + 8 * (pr >> 1) + 4 * hi + (pr & 1) * 2;
      *(unsigned*)(reg + q31 * 256 + ((e * 2) ^ swz)) = w;
    }
  size_t orow = (size_t)b * 2048 + (size_t)qt * 256 + wid * 32;
#pragma unroll
  for (int pass = 0; pass < 8; pass++) {
    int n = pass * 64 + lane;
    int q = n >> 4, ch = n & 15;
    bf16x8 v = *(const bf16x8*)(reg + q * 256 + ((ch * 16) ^ ((q & 7) << 4)));
    *(bf16x8*)((char*)(catO + (orow + q) * 1024 + h * 128) + ch * 16) = v;
  }
}

// ---------------- layernorm (row = 1024), grid-stride 8 rows/block ---------
template <int IN_BF16, int OUT_BF16>
__global__ __launch_bounds__(256) void ln_kernel(
    const void* __restrict__ in, const float* __restrict__ g,
    const float* __restrict__ be, void* __restrict__ out) {
  int tid = threadIdx.x;
  int wid = tid >> 6, lane = tid & 63;
  float4 gg = ((const float4*)g)[tid];
  float4 bb = ((const float4*)be)[tid];
  __shared__ float ws[8];
  for (int row = blockIdx.x; row < 16384; row += gridDim.x) {
    float4 v;
    if constexpr (IN_BF16) {
      ushort4 u = ((const ushort4*)in)[(size_t)row * 256 + tid];
      v.x = bfu2f(u.x); v.y = bfu2f(u.y); v.z = bfu2f(u.z); v.w = bfu2f(u.w);
    } else {
      v = ((const float4*)in)[(size_t)row * 256 + tid];
    }
    float s = v.x + v.y + v.z + v.w;
    float sq = v.x * v.x + v.y * v.y + v.z * v.z + v.w * v.w;
#pragma unroll
    for (int m = 1; m < 64; m <<= 1) {
      s += __shfl_xor(s, m);
      sq += __shfl_xor(sq, m);
    }
    if (lane == 0) { ws[wid] = s; ws[wid + 4] = sq; }
    __syncthreads();
    s = ws[0] + ws[1] + ws[2] + ws[3];
    sq = ws[4] + ws[5] + ws[6] + ws[7];
    __syncthreads();                       // ws reads done before next overwrite
    float mu = s * (1.0f / 1024.0f);
    float var = sq * (1.0f / 1024.0f) - mu * mu;
    float rs = rsqrtf(var + 1e-3f);
    float y0 = (v.x - mu) * rs * gg.x + bb.x;
    float y1 = (v.y - mu) * rs * gg.y + bb.y;
    float y2 = (v.z - mu) * rs * gg.z + bb.z;
    float y3 = (v.w - mu) * rs * gg.w + bb.w;
    if constexpr (OUT_BF16) {
      ushort4 ov;
      ov.x = f2bfu(y0); ov.y = f2bfu(y1); ov.z = f2bfu(y2); ov.w = f2bfu(y3);
      ((ushort4*)out)[(size_t)row * 256 + tid] = ov;
    } else {
      float4 ov = {y0, y1, y2, y3};
      ((float4*)out)[(size_t)row * 256 + tid] = ov;
    }
  }
}

// ---------------------------------------------------------------------------
extern "C" void kernel_launch(void* const* d_in, const int* in_sizes, int n_in,
                              void* d_out, int out_size, void* d_ws, size_t ws_size,
                              hipStream_t stream) {
  const float* query = (const float*)d_in[0];
  const float* value = (const float*)d_in[1];
  const float* W1 = (const float*)d_in[2];
  const float* W2 = (const float*)d_in[3];
  const float* W3 = (const float*)d_in[4];
  const float* Wp = (const float*)d_in[5];
  const float* bp = (const float*)d_in[6];
  const float* Wt = (const float*)d_in[7];
  const float* bt = (const float*)d_in[8];
  const float* g1 = (const float*)d_in[9];
  const float* b1 = (const float*)d_in[10];
  const float* g2 = (const float*)d_in[11];
  const float* b2 = (const float*)d_in[12];

  char* ws = (char*)d_ws;
  // lifetimes: qbf alive through G4 (residual); vbf region hosts vbf -> cat_
  // -> pln sequentially; Qh -> projb after FA; Kh -> tb after FA.
  unsigned short* qbf  = (unsigned short*)(ws + 0);           // 33.5M (live->G4)
  unsigned short* vbf  = (unsigned short*)(ws + 33554432);    // 33.5M
  unsigned short* Qh   = (unsigned short*)(ws + 67108864);    // 33.5M
  unsigned short* Kh   = (unsigned short*)(ws + 100663296);   // 33.5M
  unsigned short* Vt   = (unsigned short*)(ws + 134217728);   // 33.5M
  unsigned short* Wq_t = (unsigned short*)(ws + 167772160);   // 2M
  unsigned short* Wk_t = (unsigned short*)(ws + 169869312);   // 2M
  unsigned short* Wv_t = (unsigned short*)(ws + 171966464);   // 2M
  unsigned short* Wp_t = (unsigned short*)(ws + 174063616);   // 2M
  unsigned short* Wt_t = (unsigned short*)(ws + 176160768);   // 2M
  unsigned short* cat_  = vbf;   // vbf dead after QKV; cat consumed by G4
  unsigned short* projb = Qh;    // Qh dead after FA
  unsigned short* pln   = vbf;   // cat_ dead after G4; pln consumed by G5
  unsigned short* tb    = Kh;    // Kh dead after FA

  prep_fused<<<9216, 256, 0, stream>>>(query, value, qbf, vbf,
                                       W1, W2, W3, Wp, Wt,
                                       Wq_t, Wk_t, Wv_t, Wp_t, Wt_t);

  const float QSCALE = 0.08838834764831845f * 1.4426950408889634f;
  gemm_qkv<<<768, 512, 0, stream>>>(qbf, vbf, Wq_t, Wk_t, Wv_t,
                                    Qh, Kh, Vt, QSCALE);
  fa_kernel<<<dim3(8, 8, 8), 512, 0, stream>>>(Qh, Kh, Vt, cat_);
  gemm256_ep<2><<<256, 512, 0, stream>>>(cat_, Wp_t, projb, bp, qbf);
  ln_kernel<1, 1><<<2048, 256, 0, stream>>>(projb, g1, b1, pln);
  gemm256_ep<3><<<256, 512, 0, stream>>>(pln, Wt_t, tb, bt, pln);
  ln_kernel<1, 0><<<2048, 256, 0, stream>>>(tb, g2, b2, (float*)d_out);
}

// Round 18
// 383.986 us; speedup vs baseline: 1.0059x; 1.0059x over previous
//
#include <hip/hip_runtime.h>
#include <hip/hip_bf16.h>

// ---------------------------------------------------------------------------
// multihead_attentive_layer: bf16 MFMA pipeline  (round-18 = exact round-16
// best config; r17's grid-stride LN was null-to-negative and is reverted).
//   prep: cast q,v -> bf16 ; transpose weights -> bf16 [N][K]
//   QKV:  Qh = q@W1' (pre-scaled), Kh = v@W2', Vt = W3'' @ v^T
//   FA:   flash attention (8w x 32q, KVBLK=64, 4-deep bufs, raw-barrier +
//         interleaved staging + vmcnt(2); swapped-operand, softmax-free)
//   G4:   proj = cat @ Wp + bp + qbf(bf16 residual)  -> bf16
//   LN1 -> pln bf16 ; G5: t = relu(pln @ Wt + bt) + pln -> bf16 ; LN2 -> f32
// GEMMs: 256x256 tile, BK=64, interleaved staging + vmcnt(2), granule-XOR
// LDS swizzle, setprio (GEMM only; r11: FA setprio perturbs regalloc),
// XCD swizzle. 7 launches.
// ---------------------------------------------------------------------------

typedef __bf16 bf16x8 __attribute__((ext_vector_type(8)));
typedef float  f32x4  __attribute__((ext_vector_type(4)));
typedef float  f32x16 __attribute__((ext_vector_type(16)));
typedef unsigned u32x4 __attribute__((ext_vector_type(4)));

#define GLDS16(g, l)                                                         \
  __builtin_amdgcn_global_load_lds(                                          \
      (__attribute__((address_space(1))) void*)(g),                          \
      (__attribute__((address_space(3))) void*)(l), 16, 0, 0)

__device__ __forceinline__ unsigned short f2bfu(float f) {
  unsigned int u = __builtin_bit_cast(unsigned int, f);
  u += 0x7fffu + ((u >> 16) & 1u);   // RNE (finite values only)
  return (unsigned short)(u >> 16);
}
__device__ __forceinline__ float bfu2f(unsigned short u) {
  return __builtin_bit_cast(float, (unsigned int)u << 16);
}

// ---------------- prep: casts + weight transposes, one launch --------------
__device__ __forceinline__ void tc_body(const float* in, unsigned short* out,
                                        int R, int C, int c0, int r0,
                                        int tx, int ty) {
  __shared__ float tile[32][33];
#pragma unroll
  for (int j = 0; j < 4; j++)
    tile[ty + j * 8][tx] = in[(size_t)(r0 + ty + j * 8) * C + c0 + tx];
  __syncthreads();
#pragma unroll
  for (int j = 0; j < 4; j++)
    out[(size_t)(c0 + ty + j * 8) * R + r0 + tx] = f2bfu(tile[tx][ty + j * 8]);
}

// 1-D grid, 9216 blocks, zero waste (branch is blockIdx-uniform):
//   idx < 4096           : cast query (idx<2048) / value, grid-stride x8
//   idx in [4096, 7168)  : {W1,W2,W3} x 8 head-slices (1024x128)
//   idx in [7168, 9216)  : Wp (first 1024) / Wt, 1024x1024
__global__ __launch_bounds__(256) void prep_fused(
    const float* __restrict__ query, const float* __restrict__ value,
    unsigned short* __restrict__ qbf, unsigned short* __restrict__ vbf,
    const float* __restrict__ W1, const float* __restrict__ W2,
    const float* __restrict__ W3, const float* __restrict__ Wp,
    const float* __restrict__ Wt, unsigned short* __restrict__ O1,
    unsigned short* __restrict__ O2, unsigned short* __restrict__ O3,
    unsigned short* __restrict__ Op, unsigned short* __restrict__ Ot) {
  int idx = blockIdx.x;
  if (idx < 4096) {
    const float* in = (idx < 2048) ? query : value;
    unsigned short* out = (idx < 2048) ? qbf : vbf;
    int blk = idx & 2047;
    int i = (blk * 256 + threadIdx.x) * 4;
    const int stride = 2048 * 256 * 4;
    for (; i < 16777216; i += stride) {
      float4 v = *(const float4*)(in + i);
      ushort4 o;
      o.x = f2bfu(v.x); o.y = f2bfu(v.y); o.z = f2bfu(v.z); o.w = f2bfu(v.w);
      *(ushort4*)(out + i) = o;
    }
    return;
  }
  int t2 = idx - 4096;
  int tx = threadIdx.x & 31, ty = threadIdx.x >> 5;
  if (t2 < 3072) {
    int slice = t2 >> 7, blk = t2 & 127;
    int t = slice >> 3, s = slice & 7;
    const float* in = (t == 0 ? W1 : t == 1 ? W2 : W3) + (size_t)s * 1024 * 128;
    unsigned short* out = (t == 0 ? O1 : t == 1 ? O2 : O3) + (size_t)s * 1024 * 128;
    tc_body(in, out, 1024, 128, (blk & 3) * 32, (blk >> 2) * 32, tx, ty);
  } else {
    int idx2 = t2 - 3072;
    int zz = idx2 >> 10, blk = idx2 & 1023;
    tc_body(zz ? Wt : Wp, zz ? Ot : Op, 1024, 1024,
            (blk & 31) * 32, (blk >> 5) * 32, tx, ty);
  }
}

// --------------- GEMM 256x256 core, BK=64, interleaved staging -------------
// 512 thr = 8 waves (2M x 4N), each wave owns 128x64. LDS 128KB double buf,
// granule-XOR swizzle slot(r,g8)=g8^(r&7). Per K-tile:
//   barrier(a) [buf free] -> STAGE part0 (2 loads) -> vmcnt(2) [prev tile's
//   8 loads landed: FIFO] -> barrier(b) -> 4x {16-MFMA w/ setprio; issue
//   next stage part}.
__device__ __forceinline__ void gemm256_core(
    const char* gA, const char* gB, char* lds, f32x4 (&acc)[8][4], int tid) {
  int wid = tid >> 6, lane = tid & 63;
  int l15 = lane & 15, l4 = lane >> 4;
  int wm = (wid >> 2) * 128, wn = (wid & 3) * 64;

  // one part = 1 A-load + 1 B-load per thread (64 rows each of A and B)
  auto STAGE_PART = [&](int buf, int t, int part) {
    char* ab = lds + buf * 65536;
    char* bb = ab + 32768;
    int s = part * 512 + tid;
    int row = s >> 3;
    int g = (s & 7) ^ (row & 7);
    unsigned dst = (unsigned)((part * 512 + (tid & ~63)) * 16);
    GLDS16(gA + (size_t)row * 2048 + t * 128 + g * 16, ab + dst);
    GLDS16(gB + (size_t)row * 2048 + t * 128 + g * 16, bb + dst);
  };

#pragma unroll
  for (int p = 0; p < 4; p++) STAGE_PART(0, 0, p);

  for (int t = 0; t < 16; t++) {
    __builtin_amdgcn_sched_barrier(0);
    __builtin_amdgcn_s_barrier();            // (a) buf[(t+1)&1] free to overwrite
    if (t < 15) {
      STAGE_PART((t + 1) & 1, t + 1, 0);     // 2 loads now; parts 1-3 mid-compute
      asm volatile("s_waitcnt vmcnt(2)" ::: "memory");   // tile t fully landed
    } else {
      asm volatile("s_waitcnt vmcnt(0)" ::: "memory");
    }
    __builtin_amdgcn_s_barrier();            // (b) tile t visible to all waves
    __builtin_amdgcn_sched_barrier(0);

    const char* ab = lds + (t & 1) * 65536;
    const char* bb = ab + 32768;
#pragma unroll
    for (int kk = 0; kk < 2; kk++) {
      bf16x8 bfr[4];
#pragma unroll
      for (int nf = 0; nf < 4; nf++) {
        int r = wn + nf * 16 + l15;
        bfr[nf] = *(const bf16x8*)(bb + r * 128 + (((kk * 4 + l4) ^ (r & 7)) << 4));
      }
#pragma unroll
      for (int mh = 0; mh < 2; mh++) {
        bf16x8 af[4];
#pragma unroll
        for (int mf = 0; mf < 4; mf++) {
          int r = wm + mh * 64 + mf * 16 + l15;
          af[mf] = *(const bf16x8*)(ab + r * 128 + (((kk * 4 + l4) ^ (r & 7)) << 4));
        }
        __builtin_amdgcn_s_setprio(1);
#pragma unroll
        for (int mf = 0; mf < 4; mf++)
#pragma unroll
          for (int nf = 0; nf < 4; nf++)
            acc[mh * 4 + mf][nf] = __builtin_amdgcn_mfma_f32_16x16x32_bf16(
                af[mf], bfr[nf], acc[mh * 4 + mf][nf], 0, 0, 0);
        __builtin_amdgcn_s_setprio(0);
        int grp = kk * 2 + mh;               // 0..3
        if (t < 15 && grp < 3) STAGE_PART((t + 1) & 1, t + 1, grp + 1);
      }
    }
  }
}

// ---------------- fused QKV projections (one launch, 768 blocks) -----------
// idx < 256 : Q tile of [16384,1024] = qbf @ Wq_t^T -> Qh scatter (scaled)
// idx < 512 : K tile, vbf @ Wk_t^T -> Kh scatter
// idx >= 512: V batched [1024,2048] = Wv_t @ vbf_b^T -> Vt (ld 2048)
__global__ __launch_bounds__(512, 2) void gemm_qkv(
    const unsigned short* __restrict__ qbf, const unsigned short* __restrict__ vbf,
    const unsigned short* __restrict__ Wq_t, const unsigned short* __restrict__ Wk_t,
    const unsigned short* __restrict__ Wv_t, unsigned short* __restrict__ Qh,
    unsigned short* __restrict__ Kh, unsigned short* __restrict__ Vt,
    float qscale) {
  int nb = gridDim.x;                  // 768 (mult of 8)
  int qq = nb >> 3;
  int lin = blockIdx.x;
  int idx = (lin & 7) * qq + (lin >> 3);       // XCD-contiguous (bijective)

  const unsigned short *A, *Bt;
  unsigned short* outp;
  int m0, n0, mode;
  float sc = 1.0f;
  if (idx < 512) {
    int seg = idx >> 8;                        // 0=Q, 1=K
    int t = idx & 255;                         // 64 m-tiles x 4 n-tiles
    m0 = (t >> 2) * 256; n0 = (t & 3) * 256;
    A = seg ? vbf : qbf;
    Bt = seg ? Wk_t : Wq_t;
    outp = seg ? Kh : Qh;
    if (!seg) sc = qscale;
    mode = 0;
  } else {
    int v = idx - 512;
    int bz = v >> 5, t = v & 31;               // 4 m-tiles x 8 n-tiles
    m0 = (t >> 3) * 256; n0 = (t & 7) * 256;
    A = Wv_t;
    Bt = vbf + (size_t)bz * 2048 * 1024;
    outp = Vt + (size_t)bz * 1024 * 2048;
    mode = 1;
  }

  __shared__ alignas(16) char lds[131072];
  f32x4 acc[8][4];
#pragma unroll
  for (int i = 0; i < 8; i++)
#pragma unroll
    for (int j = 0; j < 4; j++) acc[i][j] = (f32x4){0.f, 0.f, 0.f, 0.f};

  gemm256_core((const char*)A + (size_t)m0 * 2048,
               (const char*)Bt + (size_t)n0 * 2048, lds, acc, threadIdx.x);

  int tid = threadIdx.x, wid = tid >> 6, lane = tid & 63;
  int l15 = lane & 15, l4 = lane >> 4;
  int wm = (wid >> 2) * 128, wn = (wid & 3) * 64;
#pragma unroll
  for (int mi = 0; mi < 8; mi++)
#pragma unroll
    for (int nf = 0; nf < 4; nf++)
#pragma unroll
      for (int r = 0; r < 4; r++) {
        int gm = m0 + wm + mi * 16 + l4 * 4 + r;
        int gn = n0 + wn + nf * 16 + l15;
        float v = acc[mi][nf][r];
        if (mode == 0) {
          int b = gm >> 11, s = gm & 2047, h = gn >> 7, e = gn & 127;
          outp[((((size_t)b * 8 + h) * 2048 + s) << 7) + e] = f2bfu(v * sc);
        } else {
          outp[(size_t)gm * 2048 + gn] = f2bfu(v);
        }
      }
}

// ---------------- epilogue GEMMs (G4/G5), 256 blocks -----------------------
// MODE 2: out bf16 = acc + bias[n] + bf16 extra[m,n]   (proj pre-LN)
// MODE 3: out bf16 = relu(acc+bias) + bf16 extra[m,n]  (transform pre-LN)
template <int MODE>
__global__ __launch_bounds__(512, 2) void gemm256_ep(
    const unsigned short* __restrict__ A, const unsigned short* __restrict__ Bt,
    unsigned short* __restrict__ out, const float* __restrict__ bias,
    const unsigned short* __restrict__ extra) {
  int nb = gridDim.x;                  // 256
  int qq = nb >> 3;
  int lin = blockIdx.x;
  int idx = (lin & 7) * qq + (lin >> 3);
  int m0 = (idx >> 2) * 256, n0 = (idx & 3) * 256;

  __shared__ alignas(16) char lds[131072];
  f32x4 acc[8][4];
#pragma unroll
  for (int i = 0; i < 8; i++)
#pragma unroll
    for (int j = 0; j < 4; j++) acc[i][j] = (f32x4){0.f, 0.f, 0.f, 0.f};

  gemm256_core((const char*)A + (size_t)m0 * 2048,
               (const char*)Bt + (size_t)n0 * 2048, lds, acc, threadIdx.x);

  int tid = threadIdx.x, wid = tid >> 6, lane = tid & 63;
  int l15 = lane & 15, l4 = lane >> 4;
  int wm = (wid >> 2) * 128, wn = (wid & 3) * 64;
#pragma unroll
  for (int mi = 0; mi < 8; mi++)
#pragma unroll
    for (int nf = 0; nf < 4; nf++)
#pragma unroll
      for (int r = 0; r < 4; r++) {
        int gm = m0 + wm + mi * 16 + l4 * 4 + r;
        int gn = n0 + wn + nf * 16 + l15;
        float v = acc[mi][nf][r];
        float pl = bfu2f(extra[(size_t)gm * 1024 + gn]);
        if constexpr (MODE == 2)
          out[(size_t)gm * 1024 + gn] = f2bfu(v + bias[gn] + pl);
        else
          out[(size_t)gm * 1024 + gn] = f2bfu(fmaxf(v + bias[gn], 0.0f) + pl);
      }
}

// ------------------------------- flash attention ---------------------------
// grid (H, SQ/256, B), 512 thr (8 waves x 32 q-rows). KV tiles of 64, 4-deep
// buffered (128 KiB LDS). blockIdx.x = h -> (b,h) locality per XCD (T1).
// Swapped QK^T (S^T = mfma(K,Q): q lane-local) + softmax-free exp2 (scores
// bounded ~16 in log2 units; exp2(16)=65536 safe in f32) + swapped PV with
// in-register P^T pack (cvt_pk + permlane32_swap). l summed in epilogue.
// Sync per 2-kt window (interleaved staging): lgkm drain -> sbar(a) ->
// STAGE_K(kt+2) [2 loads] -> vmcnt(2) [prev window's 8 loads landed: FIFO]
// -> sbar(b) -> QK(kt); V(kt+2); QK(kt+1); K(kt+3); PV(kt); V(kt+3); PV(kt+1)
// NO setprio here (r11 A/B: it perturbs regalloc, -8%).
// 16-granule XOR swizzle on K and V (row&15), pre-swizzled global source.
__global__ __launch_bounds__(512) void fa_kernel(
    const unsigned short* __restrict__ Qh,   // [B][H][2048][128]
    const unsigned short* __restrict__ Kh,   // [B][H][2048][128]
    const unsigned short* __restrict__ Vt,   // [B][1024][2048]
    unsigned short* __restrict__ catO) {     // [B*2048][1024]
  int h = blockIdx.x, qt = blockIdx.y, b = blockIdx.z;
  int tid = threadIdx.x, wid = tid >> 6, lane = tid & 63;
  int q31 = lane & 31, hi = lane >> 5;

  __shared__ alignas(16) char lds[131072];
  // K buf (kt&3): lds + (kt&3)*16384      (64 rows x 256B)
  // V buf (kt&3): lds + 65536 + (kt&3)*16384 (64 rows x 256B; row r halves:
  //   V^T[e=r] / V^T[e=r+64]); both XOR-swizzled granule g -> g ^ (row&15).

  const char* gK = (const char*)(Kh + (((size_t)b * 8 + h) * 2048) * 128);
  const char* gV = (const char*)(Vt + ((size_t)b * 1024 + h * 128) * 2048);

  bf16x8 qf[8];
  {
    const char* gQ = (const char*)(Qh + (((size_t)b * 8 + h) * 2048
                        + (size_t)qt * 256 + wid * 32 + q31) * 128);
#pragma unroll
    for (int ks = 0; ks < 8; ks++)
      qf[ks] = *(const bf16x8*)(gQ + ks * 32 + hi * 16);
  }

  f32x16 o[4];
#pragma unroll
  for (int et = 0; et < 4; et++)
#pragma unroll
    for (int r = 0; r < 16; r++) o[et][r] = 0.f;
  float lacc0 = 0.f, lacc1 = 0.f;

  auto STAGE_K = [&](int kt) {
    char* kb = lds + (kt & 3) * 16384;
#pragma unroll
    for (int pass = 0; pass < 2; pass++) {
      int c = pass * 512 + tid;
      int row = c >> 4, ch = c & 15;
      int g = ch ^ (row & 15);
      GLDS16(gK + (size_t)(kt * 64 + row) * 256 + g * 16,
             kb + (pass * 512 + (tid & ~63)) * 16);
    }
  };
  auto STAGE_V = [&](int kt) {
    char* vb = lds + 65536 + (kt & 3) * 16384;
#pragma unroll
    for (int pass = 0; pass < 2; pass++) {
      int c = pass * 512 + tid;
      int row = c >> 4, g = c & 15;
      int gp = g ^ (row & 15);
      int e = ((gp >> 3) << 6) + row;
      GLDS16(gV + (size_t)e * 4096 + kt * 128 + (gp & 7) * 16,
             vb + (pass * 512 + (tid & ~63)) * 16);
    }
  };
  auto QK = [&](int kt, f32x16& r0, f32x16& r1) {
    const char* kb = lds + (kt & 3) * 16384;
#pragma unroll
    for (int r = 0; r < 16; r++) { r0[r] = 0.f; r1[r] = 0.f; }
#pragma unroll
    for (int ks = 0; ks < 8; ks++) {
      int g = ((2 * ks + hi) ^ (q31 & 15)) << 4;
      bf16x8 k0 = *(const bf16x8*)(kb + q31 * 256 + g);
      bf16x8 k1 = *(const bf16x8*)(kb + (q31 + 32) * 256 + g);
      r0 = __builtin_amdgcn_mfma_f32_32x32x16_bf16(k0, qf[ks], r0, 0, 0, 0);
      r1 = __builtin_amdgcn_mfma_f32_32x32x16_bf16(k1, qf[ks], r1, 0, 0, 0);
    }
  };
  auto SOFT_PV = [&](int kt, f32x16& s0, f32x16& s1) {
    float p[32];
#pragma unroll
    for (int r = 0; r < 16; r++) p[r] = __builtin_amdgcn_exp2f(s0[r]);
#pragma unroll
    for (int r = 0; r < 16; r++) p[16 + r] = __builtin_amdgcn_exp2f(s1[r]);
#pragma unroll
    for (int r = 0; r < 16; r++) { lacc0 += p[r]; lacc1 += p[16 + r]; }
    bf16x8 pa[4];
#pragma unroll
    for (int g = 0; g < 4; g++) {
      unsigned a0, a1, b0, b1;
      float p0 = p[g * 8 + 0], p1 = p[g * 8 + 1], p2 = p[g * 8 + 2], p3 = p[g * 8 + 3];
      float p4 = p[g * 8 + 4], p5 = p[g * 8 + 5], p6 = p[g * 8 + 6], p7 = p[g * 8 + 7];
      asm("v_cvt_pk_bf16_f32 %0, %1, %2" : "=v"(a0) : "v"(p0), "v"(p1));
      asm("v_cvt_pk_bf16_f32 %0, %1, %2" : "=v"(b0) : "v"(p4), "v"(p5));
      asm("v_cvt_pk_bf16_f32 %0, %1, %2" : "=v"(a1) : "v"(p2), "v"(p3));
      asm("v_cvt_pk_bf16_f32 %0, %1, %2" : "=v"(b1) : "v"(p6), "v"(p7));
      asm volatile("v_permlane32_swap_b32 %0, %1" : "+v"(a0), "+v"(b0));
      asm volatile("v_permlane32_swap_b32 %0, %1" : "+v"(a1), "+v"(b1));
      u32x4 w; w[0] = a0; w[1] = a1; w[2] = b0; w[3] = b1;
      pa[g] = __builtin_bit_cast(bf16x8, w);
    }
    const char* vb = lds + 65536 + (kt & 3) * 16384;
#pragma unroll
    for (int et = 0; et < 4; et++) {
      int row = (et & 1) * 32 + q31;
      int gb = (et >> 1) * 8;
#pragma unroll
      for (int ks = 0; ks < 4; ks++) {
        bf16x8 vf = *(const bf16x8*)(vb + row * 256 +
                        (((gb + 2 * ks + hi) ^ (row & 15)) << 4));
        o[et] = __builtin_amdgcn_mfma_f32_32x32x16_bf16(vf, pa[ks], o[et], 0, 0, 0);
      }
    }
  };

  // prologue: K/V for kt 0,1 in flight (8 gloads/thread)
  STAGE_K(0); STAGE_V(0); STAGE_K(1); STAGE_V(1);

  for (int w = 0; w < 16; w++) {
    int kt = 2 * w;
    asm volatile("s_waitcnt lgkmcnt(0)" ::: "memory");
    __builtin_amdgcn_sched_barrier(0);
    __builtin_amdgcn_s_barrier();          // (a) reads of overwrite targets done
    if (w < 15) {
      STAGE_K(kt + 2);                     // 2 loads now; rest mid-compute
      asm volatile("s_waitcnt vmcnt(2)" ::: "memory");  // prev window landed
    } else {
      asm volatile("s_waitcnt vmcnt(0)" ::: "memory");
    }
    __builtin_amdgcn_s_barrier();          // (b) bufs kt,kt+1 visible
    __builtin_amdgcn_sched_barrier(0);
    f32x16 sA0, sA1, sB0, sB1;
    QK(kt, sA0, sA1);
    if (w < 15) STAGE_V(kt + 2);
    QK(kt + 1, sB0, sB1);
    if (w < 15) STAGE_K(kt + 3);
    SOFT_PV(kt, sA0, sA1);
    if (w < 15) STAGE_V(kt + 3);
    SOFT_PV(kt + 1, sB0, sB1);
  }

  // --- epilogue: normalize, transpose via wave-private LDS, store ---
  float lacc = lacc0 + lacc1;
  lacc += __shfl_xor(lacc, 32);
  float linv = 1.0f / lacc;
  __syncthreads();                          // all waves done with K/V buffers
  char* reg = lds + wid * 8192;             // [32 q][256B e-row], swizzled &7
  int swz = (lane & 7) << 4;
#pragma unroll
  for (int et = 0; et < 4; et++)
#pragma unroll
    for (int pr = 0; pr < 8; pr++) {
      float lo = o[et][2 * pr] * linv, hf = o[et][2 * pr + 1] * linv;
      unsigned w;
      asm("v_cvt_pk_bf16_f32 %0, %1, %2" : "=v"(w) : "v"(lo), "v"(hf));
      int e = et * 32 + 8 * (pr >> 1) + 4 * hi + (pr & 1) * 2;
      *(unsigned*)(reg + q31 * 256 + ((e * 2) ^ swz)) = w;
    }
  size_t orow = (size_t)b * 2048 + (size_t)qt * 256 + wid * 32;
#pragma unroll
  for (int pass = 0; pass < 8; pass++) {
    int n = pass * 64 + lane;
    int q = n >> 4, ch = n & 15;
    bf16x8 v = *(const bf16x8*)(reg + q * 256 + ((ch * 16) ^ ((q & 7) << 4)));
    *(bf16x8*)((char*)(catO + (orow + q) * 1024 + h * 128) + ch * 16) = v;
  }
}

// ------------------------------- layernorm (row = 1024) --------------------
template <int IN_BF16, int OUT_BF16>
__global__ __launch_bounds__(256) void ln_kernel(
    const void* __restrict__ in, const float* __restrict__ g,
    const float* __restrict__ be, void* __restrict__ out) {
  int row = blockIdx.x;
  int tid = threadIdx.x;
  float4 v;
  if constexpr (IN_BF16) {
    ushort4 u = ((const ushort4*)in)[(size_t)row * 256 + tid];
    v.x = bfu2f(u.x); v.y = bfu2f(u.y); v.z = bfu2f(u.z); v.w = bfu2f(u.w);
  } else {
    v = ((const float4*)in)[(size_t)row * 256 + tid];
  }
  float s = v.x + v.y + v.z + v.w;
  float sq = v.x * v.x + v.y * v.y + v.z * v.z + v.w * v.w;
#pragma unroll
  for (int m = 1; m < 64; m <<= 1) {
    s += __shfl_xor(s, m);
    sq += __shfl_xor(sq, m);
  }
  __shared__ float ws[8];
  int wid = tid >> 6, lane = tid & 63;
  if (lane == 0) { ws[wid] = s; ws[wid + 4] = sq; }
  __syncthreads();
  s = ws[0] + ws[1] + ws[2] + ws[3];
  sq = ws[4] + ws[5] + ws[6] + ws[7];
  float mu = s * (1.0f / 1024.0f);
  float var = sq * (1.0f / 1024.0f) - mu * mu;
  float rs = rsqrtf(var + 1e-3f);
  float4 gg = ((const float4*)g)[tid];
  float4 bb = ((const float4*)be)[tid];
  float y0 = (v.x - mu) * rs * gg.x + bb.x;
  float y1 = (v.y - mu) * rs * gg.y + bb.y;
  float y2 = (v.z - mu) * rs * gg.z + bb.z;
  float y3 = (v.w - mu) * rs * gg.w + bb.w;
  if constexpr (OUT_BF16) {
    ushort4 ov;
    ov.x = f2bfu(y0); ov.y = f2bfu(y1); ov.z = f2bfu(y2); ov.w = f2bfu(y3);
    ((ushort4*)out)[(size_t)row * 256 + tid] = ov;
  } else {
    float4 ov = {y0, y1, y2, y3};
    ((float4*)out)[(size_t)row * 256 + tid] = ov;
  }
}

// ---------------------------------------------------------------------------
extern "C" void kernel_launch(void* const* d_in, const int* in_sizes, int n_in,
                              void* d_out, int out_size, void* d_ws, size_t ws_size,
                              hipStream_t stream) {
  const float* query = (const float*)d_in[0];
  const float* value = (const float*)d_in[1];
  const float* W1 = (const float*)d_in[2];
  const float* W2 = (const float*)d_in[3];
  const float* W3 = (const float*)d_in[4];
  const float* Wp = (const float*)d_in[5];
  const float* bp = (const float*)d_in[6];
  const float* Wt = (const float*)d_in[7];
  const float* bt = (const float*)d_in[8];
  const float* g1 = (const float*)d_in[9];
  const float* b1 = (const float*)d_in[10];
  const float* g2 = (const float*)d_in[11];
  const float* b2 = (const float*)d_in[12];

  char* ws = (char*)d_ws;
  // lifetimes: qbf alive through G4 (residual); vbf region hosts vbf -> cat_
  // -> pln sequentially; Qh -> projb after FA; Kh -> tb after FA.
  unsigned short* qbf  = (unsigned short*)(ws + 0);           // 33.5M (live->G4)
  unsigned short* vbf  = (unsigned short*)(ws + 33554432);    // 33.5M
  unsigned short* Qh   = (unsigned short*)(ws + 67108864);    // 33.5M
  unsigned short* Kh   = (unsigned short*)(ws + 100663296);   // 33.5M
  unsigned short* Vt   = (unsigned short*)(ws + 134217728);   // 33.5M
  unsigned short* Wq_t = (unsigned short*)(ws + 167772160);   // 2M
  unsigned short* Wk_t = (unsigned short*)(ws + 169869312);   // 2M
  unsigned short* Wv_t = (unsigned short*)(ws + 171966464);   // 2M
  unsigned short* Wp_t = (unsigned short*)(ws + 174063616);   // 2M
  unsigned short* Wt_t = (unsigned short*)(ws + 176160768);   // 2M
  unsigned short* cat_  = vbf;   // vbf dead after QKV; cat consumed by G4
  unsigned short* projb = Qh;    // Qh dead after FA
  unsigned short* pln   = vbf;   // cat_ dead after G4; pln consumed by G5
  unsigned short* tb    = Kh;    // Kh dead after FA

  prep_fused<<<9216, 256, 0, stream>>>(query, value, qbf, vbf,
                                       W1, W2, W3, Wp, Wt,
                                       Wq_t, Wk_t, Wv_t, Wp_t, Wt_t);

  const float QSCALE = 0.08838834764831845f * 1.4426950408889634f;
  gemm_qkv<<<768, 512, 0, stream>>>(qbf, vbf, Wq_t, Wk_t, Wv_t,
                                    Qh, Kh, Vt, QSCALE);
  fa_kernel<<<dim3(8, 8, 8), 512, 0, stream>>>(Qh, Kh, Vt, cat_);
  gemm256_ep<2><<<256, 512, 0, stream>>>(cat_, Wp_t, projb, bp, qbf);
  ln_kernel<1, 1><<<16384, 256, 0, stream>>>(projb, g1, b1, pln);
  gemm256_ep<3><<<256, 512, 0, stream>>>(pln, Wt_t, tb, bt, pln);
  ln_kernel<1, 0><<<16384, 256, 0, stream>>>(tb, g2, b2, (float*)d_out);
}